// Round 5
// baseline (1934.647 us; speedup 1.0000x reference)
//
#include <hip/hip_runtime.h>
#include <hip/hip_bf16.h>

// HyperNetSIR: x(N,3) f32, H(E,N) f32 0/1 mask (density 0.002), beta(N), gamma(N), steps
// out: (steps, N, 3) f32 trajectory.
//
// R5: ONE kernel per step, no barriers, no polling. Edge-waves compute y_e,
// atomicAdd it into each member's z-slot, then (after vmcnt drain) atomicAdd
// an arrival counter; the LAST arriver performs that node's SIR update inline.
// Every reader of I[m] is an arriver at slot[m], so the updater can't clobber
// I[m] early. Launch boundaries give cross-step visibility (R1-proven).
// 49 step launches (vs 98 in R1); zero spin loops (R2/R4 lesson: polling on
// this chip costs 24-36us/sync).

#define EDGE_CAP 96   // max nodes per edge (mean 40, sigma 6.3 -> ~9 sigma headroom)

struct __align__(64) NodeSlot {   // one LLC line per node: kills RMW hot-line serialization
    float z;
    unsigned rem;
    unsigned pad[14];
};

// Zero counters + slots (both parities), unpack x into S/I/R, write traj[0].
__global__ void init_kernel(const float* __restrict__ x,
                            int* __restrict__ edge_cnt, int* __restrict__ node_cnt,
                            NodeSlot* __restrict__ slots,   // 2*n_nodes slots
                            float* __restrict__ S, float* __restrict__ I,
                            float* __restrict__ R, float* __restrict__ out0,
                            int n_edges, int n_nodes) {
    int i = blockIdx.x * blockDim.x + threadIdx.x;
    if (i < n_edges) edge_cnt[i] = 0;
    if (i < 2 * n_nodes) { slots[i].z = 0.0f; slots[i].rem = 0u; }
    if (i < n_nodes) {
        node_cnt[i] = 0;
        float s = x[i * 3 + 0], iv = x[i * 3 + 1], r = x[i * 3 + 2];
        S[i] = s; I[i] = iv; R[i] = r;
        out0[i * 3 + 0] = s; out0[i * 3 + 1] = iv; out0[i * 3 + 2] = r;
    }
}

// One block per edge row: scan H with float4 loads, build edge->node lists
// and per-node edge counts (no node->edge list needed in R5).
__global__ void build_adjacency_kernel(const float* __restrict__ H,
                                       int* __restrict__ edge_cnt,
                                       int* __restrict__ edge_nodes,
                                       int* __restrict__ node_cnt,
                                       int n_nodes) {
    const int e = blockIdx.x;
    const float* row = H + (size_t)e * n_nodes;
    const int n4 = n_nodes >> 2;
    const float4* row4 = (const float4*)row;
    for (int c4 = threadIdx.x; c4 < n4; c4 += blockDim.x) {
        float4 v = row4[c4];
        int cbase = c4 << 2;
        float vals[4] = {v.x, v.y, v.z, v.w};
        #pragma unroll
        for (int j = 0; j < 4; ++j) {
            if (vals[j] != 0.0f) {
                int c = cbase + j;
                int p = atomicAdd(&edge_cnt[e], 1);
                if (p < EDGE_CAP) edge_nodes[e * EDGE_CAP + p] = c;
                atomicAdd(&node_cnt[c], 1);
            }
        }
    }
    if (threadIdx.x == 0) {
        for (int c = n4 << 2; c < n_nodes; ++c) {
            if (row[c] != 0.0f) {
                int p = atomicAdd(&edge_cnt[e], 1);
                if (p < EDGE_CAP) edge_nodes[e * EDGE_CAP + p] = c;
                atomicAdd(&node_cnt[c], 1);
            }
        }
    }
}

__device__ __forceinline__ void update_node(int n, float zv,
                                            const float* __restrict__ beta,
                                            const float* __restrict__ gamma,
                                            float* __restrict__ S,
                                            float* __restrict__ I,
                                            float* __restrict__ R,
                                            float* __restrict__ out_t) {
    float s = S[n], iv = I[n], r = R[n];
    float nc = beta[n] * s * zv;
    float nr = gamma[n] * iv;
    float s2 = fmaxf(s - nc, 0.0f);
    float i2 = fmaxf(iv + nc - nr, 0.0f);
    float r2 = fmaxf(r + nr, 0.0f);
    float inv = 1.0f / (s2 + i2 + r2);
    s2 *= inv; i2 *= inv; r2 *= inv;
    S[n] = s2; I[n] = i2; R[n] = r2;
    out_t[n * 3 + 0] = s2; out_t[n * 3 + 1] = i2; out_t[n * 3 + 2] = r2;
}

// One fused step. Blocks [0, edge_blocks): wave per edge (gather I, reduce,
// scatter y_e via atomicAdd into z, count-down arrival -> last arriver updates
// the node). Blocks [edge_blocks, ...): tail handling isolated nodes (cnt==0).
__global__ void __launch_bounds__(256)
sir_step_kernel(const int* __restrict__ edge_cnt,
                const int* __restrict__ edge_nodes,
                const int* __restrict__ node_cnt,
                NodeSlot* __restrict__ slot,          // parity-selected base
                const float* __restrict__ beta,
                const float* __restrict__ gamma,
                float* __restrict__ S, float* __restrict__ I, float* __restrict__ R,
                float* __restrict__ out_t,
                int n_nodes, int n_edges, int edge_blocks) {
    if (blockIdx.x < edge_blocks) {
        const int wavesPerBlock = blockDim.x >> 6;
        const int e = blockIdx.x * wavesPerBlock + (threadIdx.x >> 6);
        const int lane = threadIdx.x & 63;
        if (e >= n_edges) return;

        const int cnt = min(edge_cnt[e], EDGE_CAP);
        const int* idx = edge_nodes + e * EDGE_CAP;
        const int m0 = (lane < cnt)      ? idx[lane]      : -1;
        const int m1 = (lane + 64 < cnt) ? idx[lane + 64] : -1;

        // gather + reduce y_e  (I from last kernel: launch-boundary coherent)
        float s = 0.0f;
        if (m0 >= 0) s += I[m0];
        if (m1 >= 0) s += I[m1];
        #pragma unroll
        for (int off = 32; off > 0; off >>= 1) s += __shfl_down(s, off, 64);
        const float ye = __shfl(s, 0, 64);   // broadcast to all lanes

        // scatter: z[m] += y_e (device-scope atomics execute at LLC)
        float zo0 = 0.0f, zo1 = 0.0f;
        if (m0 >= 0) zo0 = atomicAdd(&slot[m0].z, ye);
        if (m1 >= 0) zo1 = atomicAdd(&slot[m1].z, ye);
        // drain: z-adds must complete at the coherence point before arrivals
        asm volatile("s_waitcnt vmcnt(0)" :: "v"(zo0), "v"(zo1) : "memory");

        // arrival count-down; last arriver for node m performs the update
        #pragma unroll
        for (int rnd = 0; rnd < 2; ++rnd) {
            int m = (rnd == 0) ? m0 : m1;
            if (m < 0) continue;
            unsigned old = atomicAdd(&slot[m].rem, 1u);
            if ((int)old + 1 == node_cnt[m]) {
                float zv = __hip_atomic_load(&slot[m].z, __ATOMIC_RELAXED,
                                             __HIP_MEMORY_SCOPE_AGENT);
                update_node(m, zv, beta, gamma, S, I, R, out_t);
                // reset this parity's slot for reuse at step t+2
                __hip_atomic_store(&slot[m].z, 0.0f, __ATOMIC_RELAXED,
                                   __HIP_MEMORY_SCOPE_AGENT);
                __hip_atomic_store(&slot[m].rem, 0u, __ATOMIC_RELAXED,
                                   __HIP_MEMORY_SCOPE_AGENT);
            }
        }
    } else {
        // tail: isolated nodes (no edges) still evolve with z = 0
        int n = (blockIdx.x - edge_blocks) * blockDim.x + threadIdx.x;
        if (n < n_nodes && node_cnt[n] == 0)
            update_node(n, 0.0f, beta, gamma, S, I, R, out_t);
    }
}

extern "C" void kernel_launch(void* const* d_in, const int* in_sizes, int n_in,
                              void* d_out, int out_size, void* d_ws, size_t ws_size,
                              hipStream_t stream) {
    const float* x     = (const float*)d_in[0];
    const float* H     = (const float*)d_in[1];
    const float* beta  = (const float*)d_in[2];
    const float* gamma = (const float*)d_in[3];
    float* out = (float*)d_out;

    const int n_nodes = in_sizes[0] / 3;                 // 20000
    const int n_edges = in_sizes[1] / n_nodes;           // 5000
    const int steps   = out_size / in_sizes[0];          // 50

    // workspace carve-up: 64B-aligned slots first
    char* ws = (char*)d_ws;
    NodeSlot* slots   = (NodeSlot*)ws;                    ws += sizeof(NodeSlot) * 2 * (size_t)n_nodes;
    int*   edge_cnt   = (int*)ws;                         ws += (size_t)n_edges * 4;
    int*   node_cnt   = (int*)ws;                         ws += (size_t)n_nodes * 4;
    int*   edge_nodes = (int*)ws;                         ws += (size_t)n_edges * EDGE_CAP * 4;
    float* S          = (float*)ws;                       ws += (size_t)n_nodes * 4;
    float* I          = (float*)ws;                       ws += (size_t)n_nodes * 4;
    float* R          = (float*)ws;                       ws += (size_t)n_nodes * 4;

    // 1. init: zero counters + both slot parities, unpack state, traj[0]
    {
        int mx = 2 * n_nodes;  // covers slots (2N), nodes (N), edges (E)
        if (mx < n_edges) mx = n_edges;
        init_kernel<<<(mx + 255) / 256, 256, 0, stream>>>(x, edge_cnt, node_cnt, slots,
                                                          S, I, R, out, n_edges, n_nodes);
    }
    // 2. extract sparsity of H (the one unavoidable 400MB scan)
    build_adjacency_kernel<<<n_edges, 256, 0, stream>>>(H, edge_cnt, edge_nodes,
                                                        node_cnt, n_nodes);
    // 3. one fused atomic-dataflow kernel per step
    const int wavesPerBlock = 4;  // 256 threads
    const int edge_blocks = (n_edges + wavesPerBlock - 1) / wavesPerBlock;
    const int tail_blocks = (n_nodes + 255) / 256;
    for (int t = 1; t < steps; ++t) {
        sir_step_kernel<<<edge_blocks + tail_blocks, 256, 0, stream>>>(
            edge_cnt, edge_nodes, node_cnt,
            slots + (size_t)(t & 1) * n_nodes,
            beta, gamma, S, I, R,
            out + (size_t)t * n_nodes * 3,
            n_nodes, n_edges, edge_blocks);
    }
}

// Round 6
// 1867.334 us; speedup vs baseline: 1.0360x; 1.0360x over previous
//
#include <hip/hip_runtime.h>
#include <hip/hip_bf16.h>

// HyperNetSIR: x(N,3) f32, H(E,N) f32 0/1 mask (density 0.002), beta(N), gamma(N), steps
// out: (steps, N, 3) f32 trajectory.
//
// R6: persistent kernel with a RELAXED-ONLY grid barrier.
//  - Mutable shared data (I, y) moves exclusively via relaxed AGENT-scope
//    atomics -> executes at the LLC, coherent across XCDs (model validated by
//    R4's pass). No fences, no acquire => no buffer_wbl2 / buffer_inv ever.
//  - Immutable adjacency is read with plain loads: stays hot in L1/L2 across
//    all steps because nothing invalidates (R2's 36us barrier = fence+acquire
//    L2 flush/inv storms, not the counter itself).
//  - Barrier: monotonic counter, relaxed RMW arrival after vmcnt drain,
//    relaxed polling by one thread per block. 99 barriers total.
//  - Node state (S,I,R,beta,gamma) lives in registers of its owning lane for
//    the whole kernel; edge member lists live in registers of their wave.

#define EDGE_CAP 96   // max nodes per edge (mean 40, sigma 6.3 -> ~9 sigma headroom)
#define NODE_CAP 32   // max edges per node (mean 10, sigma 3.2 -> ~7 sigma headroom)
#define K_MAX 8       // max register-cached edges per edge-wave (actual <= 3)

#define GRID_BLOCKS 128
#define BLOCK_THREADS 1024

__device__ __forceinline__ float aload_f(const float* p) {
    return __hip_atomic_load(p, __ATOMIC_RELAXED, __HIP_MEMORY_SCOPE_AGENT);
}
__device__ __forceinline__ void astore_f(float* p, float v) {
    __hip_atomic_store(p, v, __ATOMIC_RELAXED, __HIP_MEMORY_SCOPE_AGENT);
}

// Relaxed-only grid barrier (monotonic counter; no fences, no cache ops).
__device__ __forceinline__ void gsync(unsigned* ctr, unsigned target) {
    asm volatile("s_waitcnt vmcnt(0)" ::: "memory");  // drain stores to LLC
    __syncthreads();
    if (threadIdx.x == 0) {
        __hip_atomic_fetch_add(ctr, 1u, __ATOMIC_RELAXED, __HIP_MEMORY_SCOPE_AGENT);
        unsigned v;
        do {
            v = __hip_atomic_load(ctr, __ATOMIC_RELAXED, __HIP_MEMORY_SCOPE_AGENT);
            if (v < target) __builtin_amdgcn_s_sleep(2);
        } while (v < target);
    }
    __syncthreads();
}

// Zero adjacency counters + barrier counter.
__global__ void zero_kernel(int* edge_cnt, int* node_cnt, unsigned* bar_ctr,
                            int n_edges, int n_nodes) {
    int i = blockIdx.x * blockDim.x + threadIdx.x;
    if (i < n_edges) edge_cnt[i] = 0;
    if (i < n_nodes) node_cnt[i] = 0;
    if (i == 0) *bar_ctr = 0u;
}

// One block per edge row: scan H with float4 loads, build both adjacencies.
__global__ void build_adjacency_kernel(const float* __restrict__ H,
                                       int* __restrict__ edge_cnt,
                                       int* __restrict__ edge_nodes,
                                       int* __restrict__ node_cnt,
                                       int* __restrict__ node_edges,
                                       int n_nodes) {
    const int e = blockIdx.x;
    const float* row = H + (size_t)e * n_nodes;
    const int n4 = n_nodes >> 2;
    const float4* row4 = (const float4*)row;
    for (int c4 = threadIdx.x; c4 < n4; c4 += blockDim.x) {
        float4 v = row4[c4];
        int cbase = c4 << 2;
        float vals[4] = {v.x, v.y, v.z, v.w};
        #pragma unroll
        for (int j = 0; j < 4; ++j) {
            if (vals[j] != 0.0f) {
                int c = cbase + j;
                int p = atomicAdd(&edge_cnt[e], 1);
                if (p < EDGE_CAP) edge_nodes[e * EDGE_CAP + p] = c;
                int q = atomicAdd(&node_cnt[c], 1);
                if (q < NODE_CAP) node_edges[c * NODE_CAP + q] = e;
            }
        }
    }
    if (threadIdx.x == 0) {
        for (int c = n4 << 2; c < n_nodes; ++c) {
            if (row[c] != 0.0f) {
                int p = atomicAdd(&edge_cnt[e], 1);
                if (p < EDGE_CAP) edge_nodes[e * EDGE_CAP + p] = c;
                int q = atomicAdd(&node_cnt[c], 1);
                if (q < NODE_CAP) node_edges[c * NODE_CAP + q] = e;
            }
        }
    }
}

// Persistent kernel: 128 blocks x 1024 threads = 2048 waves, all co-resident.
// Waves [0, 313): node-waves (lane = one node). Waves [313, 2048): edge-waves
// (<= 3 edges each, member ids register-cached).
__global__ void __launch_bounds__(BLOCK_THREADS)
sir_persist_kernel(const float* __restrict__ x,
                   const float* __restrict__ beta,
                   const float* __restrict__ gamma,
                   const int* __restrict__ edge_cnt,
                   const int* __restrict__ edge_nodes,
                   const int* __restrict__ node_cnt,
                   const int* __restrict__ node_edges,
                   float* __restrict__ I_sh,   // shared I, agent-atomic access only
                   float* __restrict__ y_sh,   // shared y, agent-atomic access only
                   float* __restrict__ out,
                   unsigned* __restrict__ bar_ctr,
                   int n_nodes, int n_edges, int steps) {
    const int wavesPerBlock = blockDim.x >> 6;
    const int wid = blockIdx.x * wavesPerBlock + (threadIdx.x >> 6);
    const int total_waves = gridDim.x * wavesPerBlock;
    const int lane = threadIdx.x & 63;
    const int node_waves = (n_nodes + 63) >> 6;
    const unsigned nblk = gridDim.x;
    unsigned barnum = 0;

    const bool is_node = wid < node_waves;

    // ---- per-role setup ----
    int n = -1; bool valid = false;
    float s = 0.f, iv = 0.f, r = 0.f, bt = 0.f, gm = 0.f;
    int ncnt = 0; const int* eidx = nullptr;
    int eown[K_MAX], m0[K_MAX], m1[K_MAX]; int kown = 0;

    if (is_node) {
        n = wid * 64 + lane;
        valid = n < n_nodes;
        if (valid) {
            s = x[n * 3 + 0]; iv = x[n * 3 + 1]; r = x[n * 3 + 2];
            bt = beta[n]; gm = gamma[n];
            ncnt = min(node_cnt[n], NODE_CAP);
            eidx = node_edges + (size_t)n * NODE_CAP;
            astore_f(&I_sh[n], iv);                    // publish I_0 at LLC
            out[n * 3 + 0] = s; out[n * 3 + 1] = iv; out[n * 3 + 2] = r;
        }
    } else {
        const int e_waves = total_waves - node_waves;
        const int ew = wid - node_waves;
        for (int e = ew; e < n_edges && kown < K_MAX; e += e_waves) {
            int c = min(edge_cnt[e], EDGE_CAP);
            const int* idx = edge_nodes + (size_t)e * EDGE_CAP;
            eown[kown] = e;
            m0[kown] = (lane < c)      ? idx[lane]      : -1;
            m1[kown] = (lane + 64 < c) ? idx[lane + 64] : -1;
            kown++;
        }
    }
    gsync(bar_ctr, (++barnum) * nblk);                 // I_0 visible at LLC

    for (int t = 1; t < steps; ++t) {
        // ---- phase A: edge-waves compute y_e = sum I[members] ----
        if (!is_node) {
            float v0[K_MAX], v1[K_MAX];
            for (int j = 0; j < kown; ++j) {           // issue all LLC loads first
                v0[j] = (m0[j] >= 0) ? aload_f(&I_sh[m0[j]]) : 0.f;
                v1[j] = (m1[j] >= 0) ? aload_f(&I_sh[m1[j]]) : 0.f;
            }
            for (int j = 0; j < kown; ++j) {
                float sv = v0[j] + v1[j];
                #pragma unroll
                for (int off = 32; off > 0; off >>= 1) sv += __shfl_down(sv, off, 64);
                if (lane == 0) astore_f(&y_sh[eown[j]], sv);
            }
        }
        gsync(bar_ctr, (++barnum) * nblk);             // all y_t at LLC

        // ---- phase B: node-lanes gather z, SIR update, publish I ----
        if (is_node && valid) {
            float z = 0.f;
            int i = 0;
            while (i < ncnt) {
                int m = min(ncnt - i, 8);
                float v[8];
                int e[8];
                for (int j = 0; j < m; ++j) {          // ids: plain loads, L1-hot
                    e[j] = eidx[i + j];
                    v[j] = aload_f(&y_sh[e[j]]);       // pipelined LLC loads
                }
                for (int j = 0; j < m; ++j) z += v[j];
                i += m;
            }
            float nc = bt * s * z;
            float nr = gm * iv;
            float s2 = fmaxf(s - nc, 0.f);
            float i2 = fmaxf(iv + nc - nr, 0.f);
            float r2 = fmaxf(r + nr, 0.f);
            float inv = 1.0f / (s2 + i2 + r2);
            s2 *= inv; i2 *= inv; r2 *= inv;
            s = s2; iv = i2; r = r2;
            astore_f(&I_sh[n], i2);                    // publish I_t at LLC
            float* o = out + (size_t)t * n_nodes * 3 + (size_t)n * 3;
            o[0] = s2; o[1] = i2; o[2] = r2;
        }
        gsync(bar_ctr, (++barnum) * nblk);             // all I_t at LLC
    }
}

extern "C" void kernel_launch(void* const* d_in, const int* in_sizes, int n_in,
                              void* d_out, int out_size, void* d_ws, size_t ws_size,
                              hipStream_t stream) {
    const float* x     = (const float*)d_in[0];
    const float* H     = (const float*)d_in[1];
    const float* beta  = (const float*)d_in[2];
    const float* gamma = (const float*)d_in[3];
    float* out = (float*)d_out;

    const int n_nodes = in_sizes[0] / 3;                 // 20000
    const int n_edges = in_sizes[1] / n_nodes;           // 5000
    const int steps   = out_size / in_sizes[0];          // 50

    // workspace carve-up (4B elements; bar_ctr on its own line)
    char* ws = (char*)d_ws;
    unsigned* bar_ctr = (unsigned*)ws;                    ws += 256;
    float* I_sh       = (float*)ws;                       ws += (size_t)n_nodes * 4;
    float* y_sh       = (float*)ws;                       ws += (size_t)n_edges * 4;
    int*   edge_cnt   = (int*)ws;                         ws += (size_t)n_edges * 4;
    int*   node_cnt   = (int*)ws;                         ws += (size_t)n_nodes * 4;
    int*   edge_nodes = (int*)ws;                         ws += (size_t)n_edges * EDGE_CAP * 4;
    int*   node_edges = (int*)ws;                         ws += (size_t)n_nodes * NODE_CAP * 4;

    // 1. zero counters (ws poisoned 0xAA before every call)
    {
        int mx = max(n_edges, n_nodes);
        zero_kernel<<<(mx + 255) / 256, 256, 0, stream>>>(edge_cnt, node_cnt, bar_ctr,
                                                          n_edges, n_nodes);
    }
    // 2. extract sparsity of H (the one unavoidable 400MB scan)
    build_adjacency_kernel<<<n_edges, 256, 0, stream>>>(H, edge_cnt, edge_nodes,
                                                        node_cnt, node_edges, n_nodes);
    // 3. persistent relaxed-barrier kernel: init + all steps
    sir_persist_kernel<<<GRID_BLOCKS, BLOCK_THREADS, 0, stream>>>(
        x, beta, gamma, edge_cnt, edge_nodes, node_cnt, node_edges,
        I_sh, y_sh, out, bar_ctr, n_nodes, n_edges, steps);
}